// Round 3
// baseline (1095.837 us; speedup 1.0000x reference)
//
#include <hip/hip_runtime.h>
#include <hip/hip_bf16.h>

#define NN 50000
#define NE 1600000
#define DIM 128
#define NG 64
#define EPSV 1e-5f
#define NCHUNK 49   // ceil(50000/1024)
#define BURST 16

typedef __attribute__((ext_vector_type(8))) __bf16 bf16x8;
typedef __attribute__((ext_vector_type(16))) float f32x16;

// ---------------- CSR build ----------------

__global__ void count_kernel(const int* __restrict__ ecol, int* __restrict__ cnt) {
    int e = blockIdx.x * 256 + threadIdx.x;
    if (e < NE) atomicAdd(&cnt[ecol[e]], 1);
}

__global__ void scan_chunk(const int* __restrict__ cnt, int* __restrict__ excl,
                           int* __restrict__ csum) {
    __shared__ int lds[256];
    int t = threadIdx.x;
    int base = blockIdx.x * 1024 + t * 4;
    int v0 = (base + 0 < NN) ? cnt[base + 0] : 0;
    int v1 = (base + 1 < NN) ? cnt[base + 1] : 0;
    int v2 = (base + 2 < NN) ? cnt[base + 2] : 0;
    int v3 = (base + 3 < NN) ? cnt[base + 3] : 0;
    int s = v0 + v1 + v2 + v3;
    lds[t] = s;
    __syncthreads();
    for (int off = 1; off < 256; off <<= 1) {
        int x = (t >= off) ? lds[t - off] : 0;
        __syncthreads();
        lds[t] += x;
        __syncthreads();
    }
    int run = lds[t] - s;           // exclusive prefix within chunk
    if (t == 255) csum[blockIdx.x] = lds[t];
    if (base + 0 < NN) excl[base + 0] = run; run += v0;
    if (base + 1 < NN) excl[base + 1] = run; run += v1;
    if (base + 2 < NN) excl[base + 2] = run; run += v2;
    if (base + 3 < NN) excl[base + 3] = run;
}

__global__ void scan_tail(const int* __restrict__ csum, int* __restrict__ coff, int nch) {
    int l = threadIdx.x;
    int v = (l < nch) ? csum[l] : 0;
    int s = v;
    for (int o = 1; o < 64; o <<= 1) {
        int x = __shfl_up(s, o);
        if (l >= o) s += x;
    }
    if (l < nch) coff[l] = s - v;   // exclusive chunk offsets
}

__global__ void fixup_kernel(int* __restrict__ row_ptr, const int* __restrict__ coff,
                             const int* __restrict__ cnt, float* __restrict__ dinv,
                             int* __restrict__ cursor) {
    int n = blockIdx.x * 256 + threadIdx.x;
    if (n < NN) {
        int rp = row_ptr[n] + coff[n >> 10];
        row_ptr[n] = rp;
        cursor[n] = rp;
        dinv[n] = rsqrtf((float)(cnt[n] + 1));   // +1 for self-loop
    }
    if (n == 0) row_ptr[NN] = NE;
}

__global__ void fill_kernel(const int* __restrict__ erow, const int* __restrict__ ecol,
                            const float* __restrict__ dinv, int* __restrict__ cursor,
                            int* __restrict__ esrc, float* __restrict__ enorm) {
    int e = blockIdx.x * 256 + threadIdx.x;
    if (e < NE) {
        int r = erow[e], c = ecol[e];
        int pos = atomicAdd(&cursor[c], 1);
        esrc[pos] = r;
        enorm[pos] = dinv[r] * dinv[c];
    }
}

// fold bias+BN into per-col scale/shift:  out = acc*scale + shift
__global__ void bn_prep_kernel(const float* __restrict__ b1, const float* __restrict__ g1,
                               const float* __restrict__ be1, const float* __restrict__ rm1,
                               const float* __restrict__ rv1,
                               const float* __restrict__ b2, const float* __restrict__ g2,
                               const float* __restrict__ be2, const float* __restrict__ rm2,
                               const float* __restrict__ rv2,
                               float* __restrict__ sc1, float* __restrict__ sh1,
                               float* __restrict__ sc2, float* __restrict__ sh2) {
    int c = threadIdx.x;
    if (c < DIM) {
        float s1 = g1[c] * rsqrtf(rv1[c] + EPSV);
        sc1[c] = s1;
        sh1[c] = (b1[c] - rm1[c]) * s1 + be1[c];
        float s2 = g2[c] * rsqrtf(rv2[c] + EPSV);
        sc2[c] = s2;
        sh2[c] = (b2[c] - rm2[c]) * s2 + be2[c];
    }
}

// ---------------- dense: h @ W -> bf16 table ----------------

__device__ __forceinline__ bf16x8 load8(const float* p) {
    float4 lo = ((const float4*)p)[0], hi = ((const float4*)p)[1];
    bf16x8 a;
    a[0] = (__bf16)lo.x; a[1] = (__bf16)lo.y; a[2] = (__bf16)lo.z; a[3] = (__bf16)lo.w;
    a[4] = (__bf16)hi.x; a[5] = (__bf16)hi.y; a[6] = (__bf16)hi.z; a[7] = (__bf16)hi.w;
    return a;
}
__device__ __forceinline__ bf16x8 load8(const __bf16* p) {
    return *(const bf16x8*)p;
}

template <typename T>
__global__ void __launch_bounds__(256) matmul_kernel(const T* __restrict__ h,
                                                     const float* __restrict__ W,
                                                     __bf16* __restrict__ t) {
    const int wave = threadIdx.x >> 6;
    const int lane = threadIdx.x & 63;
    const int col = wave * 32 + (lane & 31);
    const int khalf = (lane >> 5) * 8;   // 0 or 8

    bf16x8 b[8];
#pragma unroll
    for (int kc = 0; kc < 8; kc++) {
#pragma unroll
        for (int j = 0; j < 8; j++) {
            b[kc][j] = (__bf16)W[(kc * 16 + khalf + j) * DIM + col];
        }
    }

    const int ntiles = (NN + 31) / 32;
    for (int tile = blockIdx.x; tile < ntiles; tile += gridDim.x) {
        const int arow = tile * 32 + (lane & 31);
        const int arow_c = (arow < NN) ? arow : (NN - 1);  // clamped load; bad rows not stored
        f32x16 acc = {};
#pragma unroll
        for (int kc = 0; kc < 8; kc++) {
            bf16x8 a = load8(h + (size_t)arow_c * DIM + kc * 16 + khalf);
            acc = __builtin_amdgcn_mfma_f32_32x32x16_bf16(a, b[kc], acc, 0, 0, 0);
        }
#pragma unroll
        for (int r = 0; r < 16; r++) {
            int orow = tile * 32 + (r & 3) + 8 * (r >> 2) + 4 * (lane >> 5);
            if (orow < NN) t[(size_t)orow * DIM + col] = (__bf16)acc[r];
        }
    }
}

// ---------------- sparse: pull-gather per node ----------------
// One wave per node. Lanes split in 4 groups of 16; one dwordx4 load fetches
// 4 table rows (1 KB) per wave instruction. Each lane accumulates 8 cols
// (c0 = (lane&15)*8) for its group's edges; epilogue reduces over the 4
// groups with 2 shfl_xor. Self-loop is a virtual edge at position `end`;
// padding slots clamp to row n with weight 0 (L1-hot, ~free).
// Ping-pong double buffer keeps 2 bursts (8 dwordx4 loads) in flight.

__device__ __forceinline__ void load_idx(
    const int* __restrict__ esrc, const float* __restrict__ enorm,
    int base, int end, int n, float wself,
    int (&s)[BURST], float (&w)[BURST]) {
#pragma unroll
    for (int i = 0; i < BURST; i++) {
        const int ee = base + i;
        const bool isE = ee < end;
        const int ld = isE ? ee : 0;          // in-bounds dummy
        const int sv = esrc[ld];
        const float wv = enorm[ld];
        s[i] = isE ? sv : n;
        w[i] = isE ? wv : ((ee == end) ? wself : 0.f);
    }
}

__device__ __forceinline__ void issue4(const uint4* __restrict__ tp, const int (&s)[BURST],
                                       int k, int sub, uint4 (&u)[4]) {
#pragma unroll
    for (int j = 0; j < 4; j++) {
        const int sa = (k & 1) ? s[4 * j + 1] : s[4 * j + 0];
        const int sb = (k & 1) ? s[4 * j + 3] : s[4 * j + 2];
        const int src = (k & 2) ? sb : sa;
        u[j] = tp[(size_t)src * 16 + sub];
    }
}

__device__ __forceinline__ void consume4(const uint4 (&u)[4], const float (&w)[BURST],
                                         int k, float (&acc)[8]) {
#pragma unroll
    for (int j = 0; j < 4; j++) {
        const float wa = (k & 1) ? w[4 * j + 1] : w[4 * j + 0];
        const float wb = (k & 1) ? w[4 * j + 3] : w[4 * j + 2];
        const float wv = (k & 2) ? wb : wa;
        const uint4 q = u[j];
        acc[0] = fmaf(__uint_as_float(q.x << 16), wv, acc[0]);
        acc[1] = fmaf(__uint_as_float(q.x & 0xffff0000u), wv, acc[1]);
        acc[2] = fmaf(__uint_as_float(q.y << 16), wv, acc[2]);
        acc[3] = fmaf(__uint_as_float(q.y & 0xffff0000u), wv, acc[3]);
        acc[4] = fmaf(__uint_as_float(q.z << 16), wv, acc[4]);
        acc[5] = fmaf(__uint_as_float(q.z & 0xffff0000u), wv, acc[5]);
        acc[6] = fmaf(__uint_as_float(q.w << 16), wv, acc[6]);
        acc[7] = fmaf(__uint_as_float(q.w & 0xffff0000u), wv, acc[7]);
    }
}

__device__ __forceinline__ void gather_rows(
    const uint4* __restrict__ tp, const int* __restrict__ esrc,
    const float* __restrict__ enorm, int beg, int end, int n, float wself,
    int lane, float (&acc)[8]) {
    const int k = lane >> 4, sub = lane & 15;
    const int m = end - beg + 1;                 // + virtual self edge
    const int nb = (m + BURST - 1) / BURST;
    int sA[BURST], sB[BURST];
    float wA[BURST], wB[BURST];
    uint4 uA[4], uB[4];
    load_idx(esrc, enorm, beg, end, n, wself, sA, wA);
    issue4(tp, sA, k, sub, uA);
    for (int b = 0; b < nb; b += 2) {
        if (b + 1 < nb) {
            load_idx(esrc, enorm, beg + (b + 1) * BURST, end, n, wself, sB, wB);
            issue4(tp, sB, k, sub, uB);
        }
        consume4(uA, wA, k, acc);
        if (b + 2 < nb) {
            load_idx(esrc, enorm, beg + (b + 2) * BURST, end, n, wself, sA, wA);
            issue4(tp, sA, k, sub, uA);
        }
        if (b + 1 < nb) consume4(uB, wB, k, acc);
    }
}

__global__ void __launch_bounds__(256) gather_bn_kernel(
    const uint4* __restrict__ tp, const int* __restrict__ row_ptr,
    const int* __restrict__ esrc, const float* __restrict__ enorm,
    const float* __restrict__ dinv, const float* __restrict__ scale,
    const float* __restrict__ shift, __bf16* __restrict__ out) {
    const int lane = threadIdx.x & 63;
    const int n = __builtin_amdgcn_readfirstlane(blockIdx.x * 4 + (threadIdx.x >> 6));
    if (n >= NN) return;
    const int beg = row_ptr[n], end = row_ptr[n + 1];
    const float dv = dinv[n];
    float acc[8] = {};
    gather_rows(tp, esrc, enorm, beg, end, n, dv * dv, lane, acc);
#pragma unroll
    for (int i = 0; i < 8; i++) {
        acc[i] += __shfl_xor(acc[i], 16);
        acc[i] += __shfl_xor(acc[i], 32);
    }
    if (lane < 16) {
        const int c0 = lane * 8;
        float4 sc0 = *(const float4*)(scale + c0), sc1 = *(const float4*)(scale + c0 + 4);
        float4 sh0 = *(const float4*)(shift + c0), sh1 = *(const float4*)(shift + c0 + 4);
        bf16x8 o;
        o[0] = (__bf16)fmaxf(fmaf(acc[0], sc0.x, sh0.x), 0.f);
        o[1] = (__bf16)fmaxf(fmaf(acc[1], sc0.y, sh0.y), 0.f);
        o[2] = (__bf16)fmaxf(fmaf(acc[2], sc0.z, sh0.z), 0.f);
        o[3] = (__bf16)fmaxf(fmaf(acc[3], sc0.w, sh0.w), 0.f);
        o[4] = (__bf16)fmaxf(fmaf(acc[4], sc1.x, sh1.x), 0.f);
        o[5] = (__bf16)fmaxf(fmaf(acc[5], sc1.y, sh1.y), 0.f);
        o[6] = (__bf16)fmaxf(fmaf(acc[6], sc1.z, sh1.z), 0.f);
        o[7] = (__bf16)fmaxf(fmaf(acc[7], sc1.w, sh1.w), 0.f);
        *(bf16x8*)(out + (size_t)n * DIM + c0) = o;
    }
}

__global__ void __launch_bounds__(256) gather_pool_kernel(
    const uint4* __restrict__ tp, const int* __restrict__ row_ptr,
    const int* __restrict__ esrc, const float* __restrict__ enorm,
    const float* __restrict__ dinv, const float* __restrict__ bias,
    const int* __restrict__ batch, float* __restrict__ out) {
    const int lane = threadIdx.x & 63;
    const int n = __builtin_amdgcn_readfirstlane(blockIdx.x * 4 + (threadIdx.x >> 6));
    if (n >= NN) return;
    const int beg = row_ptr[n], end = row_ptr[n + 1];
    const float dv = dinv[n];
    float acc[8] = {};
    gather_rows(tp, esrc, enorm, beg, end, n, dv * dv, lane, acc);
#pragma unroll
    for (int i = 0; i < 8; i++) {
        acc[i] += __shfl_xor(acc[i], 16);
        acc[i] += __shfl_xor(acc[i], 32);
    }
    if (lane < 16) {
        const int c0 = lane * 8;
        float4 b0 = *(const float4*)(bias + c0), b1v = *(const float4*)(bias + c0 + 4);
        const int g = batch[n];
        float* op = out + (size_t)g * DIM + c0;
        atomicAdd(op + 0, acc[0] + b0.x);
        atomicAdd(op + 1, acc[1] + b0.y);
        atomicAdd(op + 2, acc[2] + b0.z);
        atomicAdd(op + 3, acc[3] + b0.w);
        atomicAdd(op + 4, acc[4] + b1v.x);
        atomicAdd(op + 5, acc[5] + b1v.y);
        atomicAdd(op + 6, acc[6] + b1v.z);
        atomicAdd(op + 7, acc[7] + b1v.w);
    }
}

// ---------------- launch ----------------

extern "C" void kernel_launch(void* const* d_in, const int* in_sizes, int n_in,
                              void* d_out, int out_size, void* d_ws, size_t ws_size,
                              hipStream_t stream) {
    const float* x    = (const float*)d_in[0];
    const int*   ei   = (const int*)d_in[1];
    const int*   batch= (const int*)d_in[2];
    const float* W1 = (const float*)d_in[3];
    const float* b1 = (const float*)d_in[4];
    const float* W2 = (const float*)d_in[5];
    const float* b2 = (const float*)d_in[6];
    const float* W3 = (const float*)d_in[7];
    const float* b3 = (const float*)d_in[8];
    const float* g1 = (const float*)d_in[9];
    const float* be1= (const float*)d_in[10];
    const float* rm1= (const float*)d_in[11];
    const float* rv1= (const float*)d_in[12];
    const float* g2 = (const float*)d_in[13];
    const float* be2= (const float*)d_in[14];
    const float* rm2= (const float*)d_in[15];
    const float* rv2= (const float*)d_in[16];
    const int* erow = ei;
    const int* ecol = ei + NE;

    char* ws = (char*)d_ws;
    size_t off = 0;
    auto alloc = [&](size_t bytes) -> void* {
        void* p = ws + off;
        off = (off + bytes + 255) & ~(size_t)255;
        return p;
    };
    int*    cnt     = (int*)alloc(NN * sizeof(int));
    int*    row_ptr = (int*)alloc((NN + 1) * sizeof(int));
    int*    cursor  = (int*)alloc(NN * sizeof(int));
    int*    csum    = (int*)alloc(64 * sizeof(int));
    int*    coff    = (int*)alloc(64 * sizeof(int));
    float*  dinv    = (float*)alloc(NN * sizeof(float));
    int*    esrc    = (int*)alloc(NE * sizeof(int));
    float*  enorm   = (float*)alloc(NE * sizeof(float));
    __bf16* tbuf    = (__bf16*)alloc((size_t)NN * DIM * sizeof(__bf16));
    __bf16* hbuf    = (__bf16*)alloc((size_t)NN * DIM * sizeof(__bf16));
    float*  sc1     = (float*)alloc(DIM * sizeof(float));
    float*  sh1     = (float*)alloc(DIM * sizeof(float));
    float*  sc2     = (float*)alloc(DIM * sizeof(float));
    float*  sh2     = (float*)alloc(DIM * sizeof(float));

    hipMemsetAsync(cnt, 0, NN * sizeof(int), stream);
    hipMemsetAsync(d_out, 0, NG * DIM * sizeof(float), stream);

    bn_prep_kernel<<<1, 128, 0, stream>>>(b1, g1, be1, rm1, rv1,
                                          b2, g2, be2, rm2, rv2,
                                          sc1, sh1, sc2, sh2);
    count_kernel<<<(NE + 255) / 256, 256, 0, stream>>>(ecol, cnt);
    scan_chunk<<<NCHUNK, 256, 0, stream>>>(cnt, row_ptr, csum);
    scan_tail<<<1, 64, 0, stream>>>(csum, coff, NCHUNK);
    fixup_kernel<<<(NN + 255) / 256, 256, 0, stream>>>(row_ptr, coff, cnt, dinv, cursor);
    fill_kernel<<<(NE + 255) / 256, 256, 0, stream>>>(erow, ecol, dinv, cursor, esrc, enorm);

    const uint4* tp = (const uint4*)tbuf;
    const int nblk = (NN + 3) / 4;

    matmul_kernel<float><<<512, 256, 0, stream>>>(x, W1, tbuf);
    gather_bn_kernel<<<nblk, 256, 0, stream>>>(tp, row_ptr, esrc, enorm, dinv,
                                               sc1, sh1, hbuf);
    matmul_kernel<__bf16><<<512, 256, 0, stream>>>(hbuf, W2, tbuf);
    gather_bn_kernel<<<nblk, 256, 0, stream>>>(tp, row_ptr, esrc, enorm, dinv,
                                               sc2, sh2, hbuf);
    matmul_kernel<__bf16><<<512, 256, 0, stream>>>(hbuf, W3, tbuf);
    gather_pool_kernel<<<nblk, 256, 0, stream>>>(tp, row_ptr, esrc, enorm, dinv,
                                                 b3, batch, (float*)d_out);
}

// Round 4
// 457.002 us; speedup vs baseline: 2.3979x; 2.3979x over previous
//
#include <hip/hip_runtime.h>
#include <hip/hip_bf16.h>

#define NN 50000
#define NE 1600000
#define DIM 128
#define NG 64
#define EPSV 1e-5f
#define NCHUNK 49   // ceil(50000/1024)
#define UNROLL 8
#define RUN 4       // nodes per wave in pool kernel (segment aggregation)

typedef __attribute__((ext_vector_type(8))) __bf16 bf16x8;
typedef __attribute__((ext_vector_type(2))) __bf16 bf16x2;
typedef __attribute__((ext_vector_type(16))) float f32x16;

// ---------------- CSR build ----------------

__global__ void count_kernel(const int* __restrict__ ecol, int* __restrict__ cnt) {
    int e = blockIdx.x * 256 + threadIdx.x;
    if (e < NE) atomicAdd(&cnt[ecol[e]], 1);
}

__global__ void scan_chunk(const int* __restrict__ cnt, int* __restrict__ excl,
                           int* __restrict__ csum) {
    __shared__ int lds[256];
    int t = threadIdx.x;
    int base = blockIdx.x * 1024 + t * 4;
    int v0 = (base + 0 < NN) ? cnt[base + 0] : 0;
    int v1 = (base + 1 < NN) ? cnt[base + 1] : 0;
    int v2 = (base + 2 < NN) ? cnt[base + 2] : 0;
    int v3 = (base + 3 < NN) ? cnt[base + 3] : 0;
    int s = v0 + v1 + v2 + v3;
    lds[t] = s;
    __syncthreads();
    for (int off = 1; off < 256; off <<= 1) {
        int x = (t >= off) ? lds[t - off] : 0;
        __syncthreads();
        lds[t] += x;
        __syncthreads();
    }
    int run = lds[t] - s;           // exclusive prefix within chunk
    if (t == 255) csum[blockIdx.x] = lds[t];
    if (base + 0 < NN) excl[base + 0] = run; run += v0;
    if (base + 1 < NN) excl[base + 1] = run; run += v1;
    if (base + 2 < NN) excl[base + 2] = run; run += v2;
    if (base + 3 < NN) excl[base + 3] = run;
}

__global__ void scan_tail(const int* __restrict__ csum, int* __restrict__ coff, int nch) {
    int l = threadIdx.x;
    int v = (l < nch) ? csum[l] : 0;
    int s = v;
    for (int o = 1; o < 64; o <<= 1) {
        int x = __shfl_up(s, o);
        if (l >= o) s += x;
    }
    if (l < nch) coff[l] = s - v;   // exclusive chunk offsets
}

__global__ void fixup_kernel(int* __restrict__ row_ptr, const int* __restrict__ coff,
                             const int* __restrict__ cnt, float* __restrict__ dinv,
                             int* __restrict__ cursor) {
    int n = blockIdx.x * 256 + threadIdx.x;
    if (n < NN) {
        int rp = row_ptr[n] + coff[n >> 10];
        row_ptr[n] = rp;
        cursor[n] = rp;
        dinv[n] = rsqrtf((float)(cnt[n] + 1));   // +1 for self-loop
    }
    if (n == 0) row_ptr[NN] = NE;
}

__global__ void fill_kernel(const int* __restrict__ erow, const int* __restrict__ ecol,
                            const float* __restrict__ dinv, int* __restrict__ cursor,
                            int* __restrict__ esrc, float* __restrict__ enorm) {
    int e = blockIdx.x * 256 + threadIdx.x;
    if (e < NE) {
        int r = erow[e], c = ecol[e];
        int pos = atomicAdd(&cursor[c], 1);
        esrc[pos] = r;
        enorm[pos] = dinv[r] * dinv[c];
    }
}

// fold bias+BN into per-col scale/shift:  out = acc*scale + shift
__global__ void bn_prep_kernel(const float* __restrict__ b1, const float* __restrict__ g1,
                               const float* __restrict__ be1, const float* __restrict__ rm1,
                               const float* __restrict__ rv1,
                               const float* __restrict__ b2, const float* __restrict__ g2,
                               const float* __restrict__ be2, const float* __restrict__ rm2,
                               const float* __restrict__ rv2,
                               float* __restrict__ sc1, float* __restrict__ sh1,
                               float* __restrict__ sc2, float* __restrict__ sh2) {
    int c = threadIdx.x;
    if (c < DIM) {
        float s1 = g1[c] * rsqrtf(rv1[c] + EPSV);
        sc1[c] = s1;
        sh1[c] = (b1[c] - rm1[c]) * s1 + be1[c];
        float s2 = g2[c] * rsqrtf(rv2[c] + EPSV);
        sc2[c] = s2;
        sh2[c] = (b2[c] - rm2[c]) * s2 + be2[c];
    }
}

// ---------------- dense: h @ W -> bf16 table ----------------

__device__ __forceinline__ bf16x8 load8(const float* p) {
    float4 lo = ((const float4*)p)[0], hi = ((const float4*)p)[1];
    bf16x8 a;
    a[0] = (__bf16)lo.x; a[1] = (__bf16)lo.y; a[2] = (__bf16)lo.z; a[3] = (__bf16)lo.w;
    a[4] = (__bf16)hi.x; a[5] = (__bf16)hi.y; a[6] = (__bf16)hi.z; a[7] = (__bf16)hi.w;
    return a;
}
__device__ __forceinline__ bf16x8 load8(const __bf16* p) {
    return *(const bf16x8*)p;
}

template <typename T>
__global__ void __launch_bounds__(256) matmul_kernel(const T* __restrict__ h,
                                                     const float* __restrict__ W,
                                                     __bf16* __restrict__ t) {
    const int wave = threadIdx.x >> 6;
    const int lane = threadIdx.x & 63;
    const int col = wave * 32 + (lane & 31);
    const int khalf = (lane >> 5) * 8;   // 0 or 8

    bf16x8 b[8];
#pragma unroll
    for (int kc = 0; kc < 8; kc++) {
#pragma unroll
        for (int j = 0; j < 8; j++) {
            b[kc][j] = (__bf16)W[(kc * 16 + khalf + j) * DIM + col];
        }
    }

    const int ntiles = (NN + 31) / 32;
    for (int tile = blockIdx.x; tile < ntiles; tile += gridDim.x) {
        const int arow = tile * 32 + (lane & 31);
        const int arow_c = (arow < NN) ? arow : (NN - 1);  // clamped load; bad rows not stored
        f32x16 acc = {};
#pragma unroll
        for (int kc = 0; kc < 8; kc++) {
            bf16x8 a = load8(h + (size_t)arow_c * DIM + kc * 16 + khalf);
            acc = __builtin_amdgcn_mfma_f32_32x32x16_bf16(a, b[kc], acc, 0, 0, 0);
        }
#pragma unroll
        for (int r = 0; r < 16; r++) {
            int orow = tile * 32 + (r & 3) + 8 * (r >> 2) + 4 * (lane >> 5);
            if (orow < NN) t[(size_t)orow * DIM + col] = (__bf16)acc[r];
        }
    }
}

// ---------------- sparse: pull-gather per node (round-2 proven core) ------
// One wave per node; lane handles cols {2*lane, 2*lane+1}; bf16 table read as
// u32 (64 lanes x 4B = one contiguous 256B row per instruction). Edge loop
// unrolled 8-wide with predication so 8 independent row loads are in flight.

__device__ __forceinline__ void gather_core(
    const unsigned int* __restrict__ t32, const int* __restrict__ esrc,
    const float* __restrict__ enorm, int beg, int end, int lane,
    float& ax, float& ay) {
    for (int e = beg; e < end; e += UNROLL) {
        int   s[UNROLL];
        float w[UNROLL];
        unsigned int u[UNROLL];
#pragma unroll
        for (int i = 0; i < UNROLL; i++) {
            const bool ok = (e + i) < end;
            const int  ee = ok ? (e + i) : beg;
            s[i] = esrc[ee];
            w[i] = ok ? enorm[ee] : 0.f;
        }
#pragma unroll
        for (int i = 0; i < UNROLL; i++) u[i] = t32[(size_t)s[i] * 64 + lane];
#pragma unroll
        for (int i = 0; i < UNROLL; i++) {
            ax = fmaf(__uint_as_float(u[i] << 16), w[i], ax);
            ay = fmaf(__uint_as_float(u[i] & 0xffff0000u), w[i], ay);
        }
    }
}

__global__ void __launch_bounds__(256) gather_bn_kernel(
    const unsigned int* __restrict__ t32, const int* __restrict__ row_ptr,
    const int* __restrict__ esrc, const float* __restrict__ enorm,
    const float* __restrict__ dinv, const float* __restrict__ scale,
    const float* __restrict__ shift, __bf16* __restrict__ out) {
    const int lane = threadIdx.x & 63;
    const int n = __builtin_amdgcn_readfirstlane(blockIdx.x * 4 + (threadIdx.x >> 6));
    if (n >= NN) return;
    float ax = 0.f, ay = 0.f;
    const int beg = row_ptr[n], end = row_ptr[n + 1];
    gather_core(t32, esrc, enorm, beg, end, lane, ax, ay);
    {   // self loop: norm = dinv[n]^2
        float w = dinv[n]; w *= w;
        const unsigned int u = t32[(size_t)n * 64 + lane];
        ax = fmaf(__uint_as_float(u << 16), w, ax);
        ay = fmaf(__uint_as_float(u & 0xffff0000u), w, ay);
    }
    const int c0 = lane * 2, c1 = c0 + 1;
    ax = fmaxf(fmaf(ax, scale[c0], shift[c0]), 0.f);
    ay = fmaxf(fmaf(ay, scale[c1], shift[c1]), 0.f);
    bf16x2 o; o[0] = (__bf16)ax; o[1] = (__bf16)ay;
    *(bf16x2*)(out + (size_t)n * DIM + c0) = o;
}

// Pool: batch is SORTED, so global_add_pool is a segment reduction. Each wave
// processes RUN consecutive nodes, accumulating (acc + b3) in registers, and
// flushes 2 atomic instructions per run / graph boundary (vs per node).

__global__ void __launch_bounds__(256) gather_pool_kernel(
    const unsigned int* __restrict__ t32, const int* __restrict__ row_ptr,
    const int* __restrict__ esrc, const float* __restrict__ enorm,
    const float* __restrict__ dinv, const float* __restrict__ bias,
    const int* __restrict__ batch, float* __restrict__ out) {
    const int lane = threadIdx.x & 63;
    const int wid = __builtin_amdgcn_readfirstlane(blockIdx.x * 4 + (threadIdx.x >> 6));
    const int n0 = wid * RUN;
    if (n0 >= NN) return;
    const int n1 = (n0 + RUN < NN) ? n0 + RUN : NN;
    const int c0 = lane * 2, c1 = c0 + 1;
    const float bx = bias[c0], by = bias[c1];
    float rx = 0.f, ry = 0.f;
    int g = batch[n0];
    for (int n = n0; n < n1; ++n) {
        float ax = 0.f, ay = 0.f;
        const int beg = row_ptr[n], end = row_ptr[n + 1];
        gather_core(t32, esrc, enorm, beg, end, lane, ax, ay);
        {
            float w = dinv[n]; w *= w;
            const unsigned int u = t32[(size_t)n * 64 + lane];
            ax = fmaf(__uint_as_float(u << 16), w, ax);
            ay = fmaf(__uint_as_float(u & 0xffff0000u), w, ay);
        }
        const int gn = batch[n];
        if (gn != g) {   // graph boundary: flush previous segment (uniform branch)
            atomicAdd(out + (size_t)g * DIM + c0, rx);
            atomicAdd(out + (size_t)g * DIM + c1, ry);
            rx = 0.f; ry = 0.f; g = gn;
        }
        rx += ax + bx;
        ry += ay + by;
    }
    atomicAdd(out + (size_t)g * DIM + c0, rx);
    atomicAdd(out + (size_t)g * DIM + c1, ry);
}

// ---------------- launch ----------------

extern "C" void kernel_launch(void* const* d_in, const int* in_sizes, int n_in,
                              void* d_out, int out_size, void* d_ws, size_t ws_size,
                              hipStream_t stream) {
    const float* x    = (const float*)d_in[0];
    const int*   ei   = (const int*)d_in[1];
    const int*   batch= (const int*)d_in[2];
    const float* W1 = (const float*)d_in[3];
    const float* b1 = (const float*)d_in[4];
    const float* W2 = (const float*)d_in[5];
    const float* b2 = (const float*)d_in[6];
    const float* W3 = (const float*)d_in[7];
    const float* b3 = (const float*)d_in[8];
    const float* g1 = (const float*)d_in[9];
    const float* be1= (const float*)d_in[10];
    const float* rm1= (const float*)d_in[11];
    const float* rv1= (const float*)d_in[12];
    const float* g2 = (const float*)d_in[13];
    const float* be2= (const float*)d_in[14];
    const float* rm2= (const float*)d_in[15];
    const float* rv2= (const float*)d_in[16];
    const int* erow = ei;
    const int* ecol = ei + NE;

    char* ws = (char*)d_ws;
    size_t off = 0;
    auto alloc = [&](size_t bytes) -> void* {
        void* p = ws + off;
        off = (off + bytes + 255) & ~(size_t)255;
        return p;
    };
    int*    cnt     = (int*)alloc(NN * sizeof(int));
    int*    row_ptr = (int*)alloc((NN + 1) * sizeof(int));
    int*    cursor  = (int*)alloc(NN * sizeof(int));
    int*    csum    = (int*)alloc(64 * sizeof(int));
    int*    coff    = (int*)alloc(64 * sizeof(int));
    float*  dinv    = (float*)alloc(NN * sizeof(float));
    int*    esrc    = (int*)alloc(NE * sizeof(int));
    float*  enorm   = (float*)alloc(NE * sizeof(float));
    __bf16* tbuf    = (__bf16*)alloc((size_t)NN * DIM * sizeof(__bf16));
    __bf16* hbuf    = (__bf16*)alloc((size_t)NN * DIM * sizeof(__bf16));
    float*  sc1     = (float*)alloc(DIM * sizeof(float));
    float*  sh1     = (float*)alloc(DIM * sizeof(float));
    float*  sc2     = (float*)alloc(DIM * sizeof(float));
    float*  sh2     = (float*)alloc(DIM * sizeof(float));

    hipMemsetAsync(cnt, 0, NN * sizeof(int), stream);
    hipMemsetAsync(d_out, 0, NG * DIM * sizeof(float), stream);

    bn_prep_kernel<<<1, 128, 0, stream>>>(b1, g1, be1, rm1, rv1,
                                          b2, g2, be2, rm2, rv2,
                                          sc1, sh1, sc2, sh2);
    count_kernel<<<(NE + 255) / 256, 256, 0, stream>>>(ecol, cnt);
    scan_chunk<<<NCHUNK, 256, 0, stream>>>(cnt, row_ptr, csum);
    scan_tail<<<1, 64, 0, stream>>>(csum, coff, NCHUNK);
    fixup_kernel<<<(NN + 255) / 256, 256, 0, stream>>>(row_ptr, coff, cnt, dinv, cursor);
    fill_kernel<<<(NE + 255) / 256, 256, 0, stream>>>(erow, ecol, dinv, cursor, esrc, enorm);

    const unsigned int* t32 = (const unsigned int*)tbuf;
    const int nblk = (NN + 3) / 4;
    const int nwaves_pool = (NN + RUN - 1) / RUN;
    const int nblk_pool = (nwaves_pool + 3) / 4;

    matmul_kernel<float><<<512, 256, 0, stream>>>(x, W1, tbuf);
    gather_bn_kernel<<<nblk, 256, 0, stream>>>(t32, row_ptr, esrc, enorm, dinv,
                                               sc1, sh1, hbuf);
    matmul_kernel<__bf16><<<512, 256, 0, stream>>>(hbuf, W2, tbuf);
    gather_bn_kernel<<<nblk, 256, 0, stream>>>(t32, row_ptr, esrc, enorm, dinv,
                                               sc2, sh2, hbuf);
    matmul_kernel<__bf16><<<512, 256, 0, stream>>>(hbuf, W3, tbuf);
    gather_pool_kernel<<<nblk_pool, 256, 0, stream>>>(t32, row_ptr, esrc, enorm, dinv,
                                                      b3, batch, (float*)d_out);
}

// Round 5
// 439.676 us; speedup vs baseline: 2.4924x; 1.0394x over previous
//
#include <hip/hip_runtime.h>
#include <hip/hip_bf16.h>

#define NN 50000
#define NE 1600000
#define DIM 128
#define NG 64
#define EPSV 1e-5f
#define NCHUNK 49   // ceil(50000/1024)
#define UNROLL 8
#define RUN 4       // nodes per wave in pool kernel (segment aggregation)

typedef __attribute__((ext_vector_type(8))) __bf16 bf16x8;
typedef __attribute__((ext_vector_type(2))) __bf16 bf16x2;
typedef __attribute__((ext_vector_type(16))) float f32x16;

// ---------------- CSR build ----------------

__global__ void count_kernel(const int* __restrict__ ecol, int* __restrict__ cnt) {
    int e = blockIdx.x * 256 + threadIdx.x;
    if (e < NE) atomicAdd(&cnt[ecol[e]], 1);
}

__global__ void scan_chunk(const int* __restrict__ cnt, int* __restrict__ excl,
                           int* __restrict__ csum) {
    __shared__ int lds[256];
    int t = threadIdx.x;
    int base = blockIdx.x * 1024 + t * 4;
    int v0 = (base + 0 < NN) ? cnt[base + 0] : 0;
    int v1 = (base + 1 < NN) ? cnt[base + 1] : 0;
    int v2 = (base + 2 < NN) ? cnt[base + 2] : 0;
    int v3 = (base + 3 < NN) ? cnt[base + 3] : 0;
    int s = v0 + v1 + v2 + v3;
    lds[t] = s;
    __syncthreads();
    for (int off = 1; off < 256; off <<= 1) {
        int x = (t >= off) ? lds[t - off] : 0;
        __syncthreads();
        lds[t] += x;
        __syncthreads();
    }
    int run = lds[t] - s;           // exclusive prefix within chunk
    if (t == 255) csum[blockIdx.x] = lds[t];
    if (base + 0 < NN) excl[base + 0] = run; run += v0;
    if (base + 1 < NN) excl[base + 1] = run; run += v1;
    if (base + 2 < NN) excl[base + 2] = run; run += v2;
    if (base + 3 < NN) excl[base + 3] = run;
}

__global__ void scan_tail(const int* __restrict__ csum, int* __restrict__ coff, int nch) {
    int l = threadIdx.x;
    int v = (l < nch) ? csum[l] : 0;
    int s = v;
    for (int o = 1; o < 64; o <<= 1) {
        int x = __shfl_up(s, o);
        if (l >= o) s += x;
    }
    if (l < nch) coff[l] = s - v;   // exclusive chunk offsets
}

__global__ void fixup_kernel(int* __restrict__ row_ptr, const int* __restrict__ coff,
                             const int* __restrict__ cnt, float* __restrict__ dinv,
                             int* __restrict__ cursor) {
    int n = blockIdx.x * 256 + threadIdx.x;
    if (n < NN) {
        int rp = row_ptr[n] + coff[n >> 10];
        row_ptr[n] = rp;
        cursor[n] = rp;
        dinv[n] = rsqrtf((float)(cnt[n] + 1));   // +1 for self-loop
    }
    if (n == 0) row_ptr[NN] = NE;
}

// norm factored: table rows pre-scaled by dinv[src]; gather is unweighted sum;
// epilogue multiplies by dinv[dst]. So fill only scatters esrc (4B/edge).
__global__ void fill_kernel(const int* __restrict__ erow, const int* __restrict__ ecol,
                            int* __restrict__ cursor, int* __restrict__ esrc) {
    int e = blockIdx.x * 256 + threadIdx.x;
    if (e < NE) {
        int pos = atomicAdd(&cursor[ecol[e]], 1);
        esrc[pos] = erow[e];
    }
}

// fold bias+BN into per-col scale/shift:  out = acc*scale + shift
__global__ void bn_prep_kernel(const float* __restrict__ b1, const float* __restrict__ g1,
                               const float* __restrict__ be1, const float* __restrict__ rm1,
                               const float* __restrict__ rv1,
                               const float* __restrict__ b2, const float* __restrict__ g2,
                               const float* __restrict__ be2, const float* __restrict__ rm2,
                               const float* __restrict__ rv2,
                               float* __restrict__ sc1, float* __restrict__ sh1,
                               float* __restrict__ sc2, float* __restrict__ sh2) {
    int c = threadIdx.x;
    if (c < DIM) {
        float s1 = g1[c] * rsqrtf(rv1[c] + EPSV);
        sc1[c] = s1;
        sh1[c] = (b1[c] - rm1[c]) * s1 + be1[c];
        float s2 = g2[c] * rsqrtf(rv2[c] + EPSV);
        sc2[c] = s2;
        sh2[c] = (b2[c] - rm2[c]) * s2 + be2[c];
    }
}

// ---------------- dense: (h @ W) * dinv[row] -> bf16 table ----------------

__device__ __forceinline__ bf16x8 load8(const float* p) {
    float4 lo = ((const float4*)p)[0], hi = ((const float4*)p)[1];
    bf16x8 a;
    a[0] = (__bf16)lo.x; a[1] = (__bf16)lo.y; a[2] = (__bf16)lo.z; a[3] = (__bf16)lo.w;
    a[4] = (__bf16)hi.x; a[5] = (__bf16)hi.y; a[6] = (__bf16)hi.z; a[7] = (__bf16)hi.w;
    return a;
}
__device__ __forceinline__ bf16x8 load8(const __bf16* p) {
    return *(const bf16x8*)p;
}

template <typename T>
__global__ void __launch_bounds__(256) matmul_kernel(const T* __restrict__ h,
                                                     const float* __restrict__ W,
                                                     const float* __restrict__ dinv,
                                                     __bf16* __restrict__ t) {
    const int wave = threadIdx.x >> 6;
    const int lane = threadIdx.x & 63;
    const int col = wave * 32 + (lane & 31);
    const int khalf = (lane >> 5) * 8;   // 0 or 8

    bf16x8 b[8];
#pragma unroll
    for (int kc = 0; kc < 8; kc++) {
#pragma unroll
        for (int j = 0; j < 8; j++) {
            b[kc][j] = (__bf16)W[(kc * 16 + khalf + j) * DIM + col];
        }
    }

    const int ntiles = (NN + 31) / 32;
    for (int tile = blockIdx.x; tile < ntiles; tile += gridDim.x) {
        const int arow = tile * 32 + (lane & 31);
        const int arow_c = (arow < NN) ? arow : (NN - 1);  // clamped load; bad rows not stored
        f32x16 acc = {};
#pragma unroll
        for (int kc = 0; kc < 8; kc++) {
            bf16x8 a = load8(h + (size_t)arow_c * DIM + kc * 16 + khalf);
            acc = __builtin_amdgcn_mfma_f32_32x32x16_bf16(a, b[kc], acc, 0, 0, 0);
        }
#pragma unroll
        for (int r = 0; r < 16; r++) {
            int orow = tile * 32 + (r & 3) + 8 * (r >> 2) + 4 * (lane >> 5);
            if (orow < NN) t[(size_t)orow * DIM + col] = (__bf16)(acc[r] * dinv[orow]);
        }
    }
}

// ---------------- sparse: pull-gather per node ----------------
// One wave per node; lane handles cols {2*lane, 2*lane+1}; bf16 table read as
// u32 (64 lanes x 4B = one contiguous 256B row per instruction). Edge loop
// unrolled 8-wide; padding slots re-read esrc[beg] with weight 0 (cache-hot).
// Rows are pre-scaled by dinv[src], so the sum is unweighted.

__device__ __forceinline__ void gather_core(
    const unsigned int* __restrict__ t32, const int* __restrict__ esrc,
    int beg, int end, int lane, float& ax, float& ay) {
    for (int e = beg; e < end; e += UNROLL) {
        int   s[UNROLL];
        float w[UNROLL];
        unsigned int u[UNROLL];
#pragma unroll
        for (int i = 0; i < UNROLL; i++) {
            const bool ok = (e + i) < end;
            s[i] = esrc[ok ? (e + i) : beg];
            w[i] = ok ? 1.f : 0.f;
        }
#pragma unroll
        for (int i = 0; i < UNROLL; i++) u[i] = t32[(size_t)s[i] * 64 + lane];
#pragma unroll
        for (int i = 0; i < UNROLL; i++) {
            ax = fmaf(__uint_as_float(u[i] << 16), w[i], ax);
            ay = fmaf(__uint_as_float(u[i] & 0xffff0000u), w[i], ay);
        }
    }
}

__global__ void __launch_bounds__(256) gather_bn_kernel(
    const unsigned int* __restrict__ t32, const int* __restrict__ row_ptr,
    const int* __restrict__ esrc, const float* __restrict__ dinv,
    const float* __restrict__ scale, const float* __restrict__ shift,
    __bf16* __restrict__ out) {
    const int lane = threadIdx.x & 63;
    const int n = __builtin_amdgcn_readfirstlane(blockIdx.x * 4 + (threadIdx.x >> 6));
    if (n >= NN) return;
    float ax = 0.f, ay = 0.f;
    const int beg = row_ptr[n], end = row_ptr[n + 1];
    gather_core(t32, esrc, beg, end, lane, ax, ay);
    {   // self loop contributes t'[n] (weight 1; dinv[n] applied below)
        const unsigned int u = t32[(size_t)n * 64 + lane];
        ax += __uint_as_float(u << 16);
        ay += __uint_as_float(u & 0xffff0000u);
    }
    const float dv = dinv[n];
    const int c0 = lane * 2, c1 = c0 + 1;
    ax = fmaxf(fmaf(ax, dv * scale[c0], shift[c0]), 0.f);
    ay = fmaxf(fmaf(ay, dv * scale[c1], shift[c1]), 0.f);
    bf16x2 o; o[0] = (__bf16)ax; o[1] = (__bf16)ay;
    *(bf16x2*)(out + (size_t)n * DIM + c0) = o;
}

// Pool: batch is SORTED -> segment reduction; flush atomics only at run end /
// graph boundary.

__global__ void __launch_bounds__(256) gather_pool_kernel(
    const unsigned int* __restrict__ t32, const int* __restrict__ row_ptr,
    const int* __restrict__ esrc, const float* __restrict__ dinv,
    const float* __restrict__ bias, const int* __restrict__ batch,
    float* __restrict__ out) {
    const int lane = threadIdx.x & 63;
    const int wid = __builtin_amdgcn_readfirstlane(blockIdx.x * 4 + (threadIdx.x >> 6));
    const int n0 = wid * RUN;
    if (n0 >= NN) return;
    const int n1 = (n0 + RUN < NN) ? n0 + RUN : NN;
    const int c0 = lane * 2, c1 = c0 + 1;
    const float bx = bias[c0], by = bias[c1];
    float rx = 0.f, ry = 0.f;
    int g = batch[n0];
    for (int n = n0; n < n1; ++n) {
        float ax = 0.f, ay = 0.f;
        const int beg = row_ptr[n], end = row_ptr[n + 1];
        gather_core(t32, esrc, beg, end, lane, ax, ay);
        {
            const unsigned int u = t32[(size_t)n * 64 + lane];
            ax += __uint_as_float(u << 16);
            ay += __uint_as_float(u & 0xffff0000u);
        }
        const float dv = dinv[n];
        const int gn = batch[n];
        if (gn != g) {   // graph boundary: flush previous segment (uniform branch)
            atomicAdd(out + (size_t)g * DIM + c0, rx);
            atomicAdd(out + (size_t)g * DIM + c1, ry);
            rx = 0.f; ry = 0.f; g = gn;
        }
        rx += fmaf(ax, dv, bx);
        ry += fmaf(ay, dv, by);
    }
    atomicAdd(out + (size_t)g * DIM + c0, rx);
    atomicAdd(out + (size_t)g * DIM + c1, ry);
}

// ---------------- launch ----------------

extern "C" void kernel_launch(void* const* d_in, const int* in_sizes, int n_in,
                              void* d_out, int out_size, void* d_ws, size_t ws_size,
                              hipStream_t stream) {
    const float* x    = (const float*)d_in[0];
    const int*   ei   = (const int*)d_in[1];
    const int*   batch= (const int*)d_in[2];
    const float* W1 = (const float*)d_in[3];
    const float* b1 = (const float*)d_in[4];
    const float* W2 = (const float*)d_in[5];
    const float* b2 = (const float*)d_in[6];
    const float* W3 = (const float*)d_in[7];
    const float* b3 = (const float*)d_in[8];
    const float* g1 = (const float*)d_in[9];
    const float* be1= (const float*)d_in[10];
    const float* rm1= (const float*)d_in[11];
    const float* rv1= (const float*)d_in[12];
    const float* g2 = (const float*)d_in[13];
    const float* be2= (const float*)d_in[14];
    const float* rm2= (const float*)d_in[15];
    const float* rv2= (const float*)d_in[16];
    const int* erow = ei;
    const int* ecol = ei + NE;

    char* ws = (char*)d_ws;
    size_t off = 0;
    auto alloc = [&](size_t bytes) -> void* {
        void* p = ws + off;
        off = (off + bytes + 255) & ~(size_t)255;
        return p;
    };
    int*    cnt     = (int*)alloc(NN * sizeof(int));
    int*    row_ptr = (int*)alloc((NN + 1) * sizeof(int));
    int*    cursor  = (int*)alloc(NN * sizeof(int));
    int*    csum    = (int*)alloc(64 * sizeof(int));
    int*    coff    = (int*)alloc(64 * sizeof(int));
    float*  dinv    = (float*)alloc(NN * sizeof(float));
    int*    esrc    = (int*)alloc(NE * sizeof(int));
    __bf16* tbuf    = (__bf16*)alloc((size_t)NN * DIM * sizeof(__bf16));
    __bf16* hbuf    = (__bf16*)alloc((size_t)NN * DIM * sizeof(__bf16));
    float*  sc1     = (float*)alloc(DIM * sizeof(float));
    float*  sh1     = (float*)alloc(DIM * sizeof(float));
    float*  sc2     = (float*)alloc(DIM * sizeof(float));
    float*  sh2     = (float*)alloc(DIM * sizeof(float));

    hipMemsetAsync(cnt, 0, NN * sizeof(int), stream);
    hipMemsetAsync(d_out, 0, NG * DIM * sizeof(float), stream);

    bn_prep_kernel<<<1, 128, 0, stream>>>(b1, g1, be1, rm1, rv1,
                                          b2, g2, be2, rm2, rv2,
                                          sc1, sh1, sc2, sh2);
    count_kernel<<<(NE + 255) / 256, 256, 0, stream>>>(ecol, cnt);
    scan_chunk<<<NCHUNK, 256, 0, stream>>>(cnt, row_ptr, csum);
    scan_tail<<<1, 64, 0, stream>>>(csum, coff, NCHUNK);
    fixup_kernel<<<(NN + 255) / 256, 256, 0, stream>>>(row_ptr, coff, cnt, dinv, cursor);
    fill_kernel<<<(NE + 255) / 256, 256, 0, stream>>>(erow, ecol, cursor, esrc);

    const unsigned int* t32 = (const unsigned int*)tbuf;
    const int nblk = (NN + 3) / 4;
    const int nwaves_pool = (NN + RUN - 1) / RUN;
    const int nblk_pool = (nwaves_pool + 3) / 4;

    matmul_kernel<float><<<512, 256, 0, stream>>>(x, W1, dinv, tbuf);
    gather_bn_kernel<<<nblk, 256, 0, stream>>>(t32, row_ptr, esrc, dinv,
                                               sc1, sh1, hbuf);
    matmul_kernel<__bf16><<<512, 256, 0, stream>>>(hbuf, W2, dinv, tbuf);
    gather_bn_kernel<<<nblk, 256, 0, stream>>>(t32, row_ptr, esrc, dinv,
                                               sc2, sh2, hbuf);
    matmul_kernel<__bf16><<<512, 256, 0, stream>>>(hbuf, W3, dinv, tbuf);
    gather_pool_kernel<<<nblk_pool, 256, 0, stream>>>(t32, row_ptr, esrc, dinv,
                                                      b3, batch, (float*)d_out);
}

// Round 6
// 401.891 us; speedup vs baseline: 2.7267x; 1.0940x over previous
//
#include <hip/hip_runtime.h>
#include <hip/hip_bf16.h>

#define NN 50000
#define NE 1600000
#define DIM 128
#define NG 64
#define EPSV 1e-5f
#define NCHUNK 49   // ceil(50000/1024)
#define UNROLL 8
#define RUN 4       // nodes per wave in pool kernel (segment aggregation)
#define NXCD 8
#define SHARD_COLS (NN / NXCD)   // 6250
#define FILL_CHUNKS 256          // edge chunks; grid = 8 * FILL_CHUNKS

typedef __attribute__((ext_vector_type(8))) __bf16 bf16x8;
typedef __attribute__((ext_vector_type(2))) __bf16 bf16x2;
typedef __attribute__((ext_vector_type(16))) float f32x16;

// ---------------- CSR build ----------------

__global__ void count_kernel(const int* __restrict__ ecol, int* __restrict__ cnt) {
    int e = blockIdx.x * 256 + threadIdx.x;
    if (e < NE) atomicAdd(&cnt[ecol[e]], 1);
}

__global__ void scan_chunk(const int* __restrict__ cnt, int* __restrict__ excl,
                           int* __restrict__ csum) {
    __shared__ int lds[256];
    int t = threadIdx.x;
    int base = blockIdx.x * 1024 + t * 4;
    int v0 = (base + 0 < NN) ? cnt[base + 0] : 0;
    int v1 = (base + 1 < NN) ? cnt[base + 1] : 0;
    int v2 = (base + 2 < NN) ? cnt[base + 2] : 0;
    int v3 = (base + 3 < NN) ? cnt[base + 3] : 0;
    int s = v0 + v1 + v2 + v3;
    lds[t] = s;
    __syncthreads();
    for (int off = 1; off < 256; off <<= 1) {
        int x = (t >= off) ? lds[t - off] : 0;
        __syncthreads();
        lds[t] += x;
        __syncthreads();
    }
    int run = lds[t] - s;           // exclusive prefix within chunk
    if (t == 255) csum[blockIdx.x] = lds[t];
    if (base + 0 < NN) excl[base + 0] = run; run += v0;
    if (base + 1 < NN) excl[base + 1] = run; run += v1;
    if (base + 2 < NN) excl[base + 2] = run; run += v2;
    if (base + 3 < NN) excl[base + 3] = run;
}

__global__ void scan_tail(const int* __restrict__ csum, int* __restrict__ coff, int nch) {
    int l = threadIdx.x;
    int v = (l < nch) ? csum[l] : 0;
    int s = v;
    for (int o = 1; o < 64; o <<= 1) {
        int x = __shfl_up(s, o);
        if (l >= o) s += x;
    }
    if (l < nch) coff[l] = s - v;   // exclusive chunk offsets
}

__global__ void fixup_kernel(int* __restrict__ row_ptr, const int* __restrict__ coff,
                             const int* __restrict__ cnt, float* __restrict__ dinv,
                             int* __restrict__ cursor) {
    int n = blockIdx.x * 256 + threadIdx.x;
    if (n < NN) {
        int rp = row_ptr[n] + coff[n >> 10];
        row_ptr[n] = rp;
        cursor[n] = rp;
        dinv[n] = rsqrtf((float)(cnt[n] + 1));   // +1 for self-loop
    }
    if (n == 0) row_ptr[NN] = NE;
}

// XCD-sharded scatter: block b handles col-shard (b&7) over edge-chunk (b>>3).
// Each esrc line / cursor line is then written by exactly one XCD (round-robin
// blockIdx->XCD heuristic), so scattered 4B stores accumulate into full lines
// in that XCD's L2 instead of 1.6M partial-line DRAM writebacks.
__global__ void fill_kernel(const int* __restrict__ erow, const int* __restrict__ ecol,
                            int* __restrict__ cursor, int* __restrict__ esrc) {
    const int shard = blockIdx.x & (NXCD - 1);
    const int chunk = blockIdx.x >> 3;
    const int lo = shard * SHARD_COLS;
    const int hi = lo + SHARD_COLS;       // NN divisible by 8
    for (int e = chunk * 256 + threadIdx.x; e < NE; e += FILL_CHUNKS * 256) {
        const int c = ecol[e];
        if (c >= lo && c < hi) {
            int pos = atomicAdd(&cursor[c], 1);
            esrc[pos] = erow[e];
        }
    }
}

// fold bias+BN into per-col scale/shift:  out = acc*scale + shift
__global__ void bn_prep_kernel(const float* __restrict__ b1, const float* __restrict__ g1,
                               const float* __restrict__ be1, const float* __restrict__ rm1,
                               const float* __restrict__ rv1,
                               const float* __restrict__ b2, const float* __restrict__ g2,
                               const float* __restrict__ be2, const float* __restrict__ rm2,
                               const float* __restrict__ rv2,
                               float* __restrict__ sc1, float* __restrict__ sh1,
                               float* __restrict__ sc2, float* __restrict__ sh2) {
    int c = threadIdx.x;
    if (c < DIM) {
        float s1 = g1[c] * rsqrtf(rv1[c] + EPSV);
        sc1[c] = s1;
        sh1[c] = (b1[c] - rm1[c]) * s1 + be1[c];
        float s2 = g2[c] * rsqrtf(rv2[c] + EPSV);
        sc2[c] = s2;
        sh2[c] = (b2[c] - rm2[c]) * s2 + be2[c];
    }
}

// ---------------- dense: (h @ W) * dinv[row] -> bf16 table ----------------

__device__ __forceinline__ bf16x8 load8(const float* p) {
    float4 lo = ((const float4*)p)[0], hi = ((const float4*)p)[1];
    bf16x8 a;
    a[0] = (__bf16)lo.x; a[1] = (__bf16)lo.y; a[2] = (__bf16)lo.z; a[3] = (__bf16)lo.w;
    a[4] = (__bf16)hi.x; a[5] = (__bf16)hi.y; a[6] = (__bf16)hi.z; a[7] = (__bf16)hi.w;
    return a;
}
__device__ __forceinline__ bf16x8 load8(const __bf16* p) {
    return *(const bf16x8*)p;
}

template <typename T>
__global__ void __launch_bounds__(256) matmul_kernel(const T* __restrict__ h,
                                                     const float* __restrict__ W,
                                                     const float* __restrict__ dinv,
                                                     __bf16* __restrict__ t) {
    const int wave = threadIdx.x >> 6;
    const int lane = threadIdx.x & 63;
    const int col = wave * 32 + (lane & 31);
    const int khalf = (lane >> 5) * 8;   // 0 or 8

    bf16x8 b[8];
#pragma unroll
    for (int kc = 0; kc < 8; kc++) {
#pragma unroll
        for (int j = 0; j < 8; j++) {
            b[kc][j] = (__bf16)W[(kc * 16 + khalf + j) * DIM + col];
        }
    }

    const int ntiles = (NN + 31) / 32;
    for (int tile = blockIdx.x; tile < ntiles; tile += gridDim.x) {
        const int arow = tile * 32 + (lane & 31);
        const int arow_c = (arow < NN) ? arow : (NN - 1);  // clamped load; bad rows not stored
        f32x16 acc = {};
#pragma unroll
        for (int kc = 0; kc < 8; kc++) {
            bf16x8 a = load8(h + (size_t)arow_c * DIM + kc * 16 + khalf);
            acc = __builtin_amdgcn_mfma_f32_32x32x16_bf16(a, b[kc], acc, 0, 0, 0);
        }
#pragma unroll
        for (int r = 0; r < 16; r++) {
            int orow = tile * 32 + (r & 3) + 8 * (r >> 2) + 4 * (lane >> 5);
            if (orow < NN) t[(size_t)orow * DIM + col] = (__bf16)(acc[r] * dinv[orow]);
        }
    }
}

// ---------------- sparse: pull-gather per node ----------------
// One wave per node; lane handles cols {2*lane, 2*lane+1}; bf16 table read as
// u32 (64 lanes x 4B = one contiguous 256B row per instruction). Edge loop
// unrolled 8-wide; padding slots re-read esrc[beg] with weight 0 (cache-hot).
// Rows are pre-scaled by dinv[src], so the sum is unweighted.

__device__ __forceinline__ void gather_core(
    const unsigned int* __restrict__ t32, const int* __restrict__ esrc,
    int beg, int end, int lane, float& ax, float& ay) {
    for (int e = beg; e < end; e += UNROLL) {
        int   s[UNROLL];
        float w[UNROLL];
        unsigned int u[UNROLL];
#pragma unroll
        for (int i = 0; i < UNROLL; i++) {
            const bool ok = (e + i) < end;
            s[i] = esrc[ok ? (e + i) : beg];
            w[i] = ok ? 1.f : 0.f;
        }
#pragma unroll
        for (int i = 0; i < UNROLL; i++) u[i] = t32[(size_t)s[i] * 64 + lane];
#pragma unroll
        for (int i = 0; i < UNROLL; i++) {
            ax = fmaf(__uint_as_float(u[i] << 16), w[i], ax);
            ay = fmaf(__uint_as_float(u[i] & 0xffff0000u), w[i], ay);
        }
    }
}

__global__ void __launch_bounds__(256) gather_bn_kernel(
    const unsigned int* __restrict__ t32, const int* __restrict__ row_ptr,
    const int* __restrict__ esrc, const float* __restrict__ dinv,
    const float* __restrict__ scale, const float* __restrict__ shift,
    __bf16* __restrict__ out) {
    const int lane = threadIdx.x & 63;
    const int n = __builtin_amdgcn_readfirstlane(blockIdx.x * 4 + (threadIdx.x >> 6));
    if (n >= NN) return;
    float ax = 0.f, ay = 0.f;
    const int beg = row_ptr[n], end = row_ptr[n + 1];
    gather_core(t32, esrc, beg, end, lane, ax, ay);
    {   // self loop contributes t'[n] (weight 1; dinv[n] applied below)
        const unsigned int u = t32[(size_t)n * 64 + lane];
        ax += __uint_as_float(u << 16);
        ay += __uint_as_float(u & 0xffff0000u);
    }
    const float dv = dinv[n];
    const int c0 = lane * 2, c1 = c0 + 1;
    ax = fmaxf(fmaf(ax, dv * scale[c0], shift[c0]), 0.f);
    ay = fmaxf(fmaf(ay, dv * scale[c1], shift[c1]), 0.f);
    bf16x2 o; o[0] = (__bf16)ax; o[1] = (__bf16)ay;
    *(bf16x2*)(out + (size_t)n * DIM + c0) = o;
}

// Pool: batch is SORTED -> segment reduction; flush atomics only at run end /
// graph boundary.

__global__ void __launch_bounds__(256) gather_pool_kernel(
    const unsigned int* __restrict__ t32, const int* __restrict__ row_ptr,
    const int* __restrict__ esrc, const float* __restrict__ dinv,
    const float* __restrict__ bias, const int* __restrict__ batch,
    float* __restrict__ out) {
    const int lane = threadIdx.x & 63;
    const int wid = __builtin_amdgcn_readfirstlane(blockIdx.x * 4 + (threadIdx.x >> 6));
    const int n0 = wid * RUN;
    if (n0 >= NN) return;
    const int n1 = (n0 + RUN < NN) ? n0 + RUN : NN;
    const int c0 = lane * 2, c1 = c0 + 1;
    const float bx = bias[c0], by = bias[c1];
    float rx = 0.f, ry = 0.f;
    int g = batch[n0];
    for (int n = n0; n < n1; ++n) {
        float ax = 0.f, ay = 0.f;
        const int beg = row_ptr[n], end = row_ptr[n + 1];
        gather_core(t32, esrc, beg, end, lane, ax, ay);
        {
            const unsigned int u = t32[(size_t)n * 64 + lane];
            ax += __uint_as_float(u << 16);
            ay += __uint_as_float(u & 0xffff0000u);
        }
        const float dv = dinv[n];
        const int gn = batch[n];
        if (gn != g) {   // graph boundary: flush previous segment (uniform branch)
            atomicAdd(out + (size_t)g * DIM + c0, rx);
            atomicAdd(out + (size_t)g * DIM + c1, ry);
            rx = 0.f; ry = 0.f; g = gn;
        }
        rx += fmaf(ax, dv, bx);
        ry += fmaf(ay, dv, by);
    }
    atomicAdd(out + (size_t)g * DIM + c0, rx);
    atomicAdd(out + (size_t)g * DIM + c1, ry);
}

// ---------------- launch ----------------

extern "C" void kernel_launch(void* const* d_in, const int* in_sizes, int n_in,
                              void* d_out, int out_size, void* d_ws, size_t ws_size,
                              hipStream_t stream) {
    const float* x    = (const float*)d_in[0];
    const int*   ei   = (const int*)d_in[1];
    const int*   batch= (const int*)d_in[2];
    const float* W1 = (const float*)d_in[3];
    const float* b1 = (const float*)d_in[4];
    const float* W2 = (const float*)d_in[5];
    const float* b2 = (const float*)d_in[6];
    const float* W3 = (const float*)d_in[7];
    const float* b3 = (const float*)d_in[8];
    const float* g1 = (const float*)d_in[9];
    const float* be1= (const float*)d_in[10];
    const float* rm1= (const float*)d_in[11];
    const float* rv1= (const float*)d_in[12];
    const float* g2 = (const float*)d_in[13];
    const float* be2= (const float*)d_in[14];
    const float* rm2= (const float*)d_in[15];
    const float* rv2= (const float*)d_in[16];
    const int* erow = ei;
    const int* ecol = ei + NE;

    char* ws = (char*)d_ws;
    size_t off = 0;
    auto alloc = [&](size_t bytes) -> void* {
        void* p = ws + off;
        off = (off + bytes + 255) & ~(size_t)255;
        return p;
    };
    int*    cnt     = (int*)alloc(NN * sizeof(int));
    int*    row_ptr = (int*)alloc((NN + 1) * sizeof(int));
    int*    cursor  = (int*)alloc(NN * sizeof(int));
    int*    csum    = (int*)alloc(64 * sizeof(int));
    int*    coff    = (int*)alloc(64 * sizeof(int));
    float*  dinv    = (float*)alloc(NN * sizeof(float));
    int*    esrc    = (int*)alloc(NE * sizeof(int));
    __bf16* tbuf    = (__bf16*)alloc((size_t)NN * DIM * sizeof(__bf16));
    __bf16* hbuf    = (__bf16*)alloc((size_t)NN * DIM * sizeof(__bf16));
    float*  sc1     = (float*)alloc(DIM * sizeof(float));
    float*  sh1     = (float*)alloc(DIM * sizeof(float));
    float*  sc2     = (float*)alloc(DIM * sizeof(float));
    float*  sh2     = (float*)alloc(DIM * sizeof(float));

    hipMemsetAsync(cnt, 0, NN * sizeof(int), stream);
    hipMemsetAsync(d_out, 0, NG * DIM * sizeof(float), stream);

    bn_prep_kernel<<<1, 128, 0, stream>>>(b1, g1, be1, rm1, rv1,
                                          b2, g2, be2, rm2, rv2,
                                          sc1, sh1, sc2, sh2);
    count_kernel<<<(NE + 255) / 256, 256, 0, stream>>>(ecol, cnt);
    scan_chunk<<<NCHUNK, 256, 0, stream>>>(cnt, row_ptr, csum);
    scan_tail<<<1, 64, 0, stream>>>(csum, coff, NCHUNK);
    fixup_kernel<<<(NN + 255) / 256, 256, 0, stream>>>(row_ptr, coff, cnt, dinv, cursor);
    fill_kernel<<<NXCD * FILL_CHUNKS, 256, 0, stream>>>(erow, ecol, cursor, esrc);

    const unsigned int* t32 = (const unsigned int*)tbuf;
    const int nblk = (NN + 3) / 4;
    const int nwaves_pool = (NN + RUN - 1) / RUN;
    const int nblk_pool = (nwaves_pool + 3) / 4;

    matmul_kernel<float><<<512, 256, 0, stream>>>(x, W1, dinv, tbuf);
    gather_bn_kernel<<<nblk, 256, 0, stream>>>(t32, row_ptr, esrc, dinv,
                                               sc1, sh1, hbuf);
    matmul_kernel<__bf16><<<512, 256, 0, stream>>>(hbuf, W2, dinv, tbuf);
    gather_bn_kernel<<<nblk, 256, 0, stream>>>(t32, row_ptr, esrc, dinv,
                                               sc2, sh2, hbuf);
    matmul_kernel<__bf16><<<512, 256, 0, stream>>>(hbuf, W3, dinv, tbuf);
    gather_pool_kernel<<<nblk_pool, 256, 0, stream>>>(t32, row_ptr, esrc, dinv,
                                                      b3, batch, (float*)d_out);
}